// Round 15
// baseline (134014.600 us; speedup 1.0000x reference)
//
#include <hip/hip_runtime.h>

#define S_LEN 4096
#define BATCH 16
#define HDIM  512
#define NSLICE 8                                   // blocks per batch
#define OUT_MAIN ((size_t)BATCH * S_LEN * HDIM)    // 33,554,432 f32 elements

// ws layout (ws proven >= 304MB by r10 pathA execution):
//   [0, 33554432)        spikes u8 [S][B][H]
//   [33554432, +134217728) ic f32 [B*S][H]
//   [IC+.. , +65536)     h_state f32 [2][B][H] ping-pong
//   [.. , +256)          bar u32[16]
#define WS_SPK   ((size_t)0)
#define WS_IC    ((size_t)33554432)
#define WS_HST   (WS_IC + (size_t)134217728)
#define WS_BAR   (WS_HST + (size_t)65536)
#define WS_NEED  (WS_BAR + (size_t)256)

// ---------------------------------------------------------------------------
// ic[b*S+t][j] = (sequential-d chain of fadd(fmul(x,w))) + bi[j]  — np-exact
// ---------------------------------------------------------------------------
__global__ __launch_bounds__(256, 2)
void ic_gemm(const float* __restrict__ x, const float* __restrict__ Wi,
             const float* __restrict__ bi, float* __restrict__ ic)
{
    const int r0  = blockIdx.x * 16;          // rows over B*S
    const int j0  = blockIdx.y * 64;
    const int tid = threadIdx.x;
    const int jj  = tid & 63, ts = tid >> 6;

    __shared__ float xs[16][512];
#pragma unroll
    for (int kr = 0; kr < 32; ++kr) {
        int i = tid + 256 * kr;
        xs[i >> 9][i & 511] = x[(size_t)r0 * HDIM + i];
    }
    __syncthreads();

    float a0 = 0.f, a1 = 0.f, a2 = 0.f, a3 = 0.f;
    const float* wj = Wi + j0 + jj;
#pragma unroll 8
    for (int d = 0; d < HDIM; ++d) {
        const float w = wj[(size_t)d * HDIM];
        a0 = __fadd_rn(a0, __fmul_rn(xs[ts * 4 + 0][d], w));
        a1 = __fadd_rn(a1, __fmul_rn(xs[ts * 4 + 1][d], w));
        a2 = __fadd_rn(a2, __fmul_rn(xs[ts * 4 + 2][d], w));
        a3 = __fadd_rn(a3, __fmul_rn(xs[ts * 4 + 3][d], w));
    }
    const float bv = bi[j0 + jj];
    ic[(size_t)(r0 + ts * 4 + 0) * HDIM + j0 + jj] = __fadd_rn(a0, bv);
    ic[(size_t)(r0 + ts * 4 + 1) * HDIM + j0 + jj] = __fadd_rn(a1, bv);
    ic[(size_t)(r0 + ts * 4 + 2) * HDIM + j0 + jj] = __fadd_rn(a2, bv);
    ic[(size_t)(r0 + ts * 4 + 3) * HDIM + j0 + jj] = __fadd_rn(a3, bv);
}

// ---------------------------------------------------------------------------
// Scan: 8 blocks/batch x 64 channels, Wh slice resident in LDS (loaded once).
// Chain threads tid<64 run the np-exact sequential-k FMA chain per channel.
// Cross-block h exchange: global f32 ping-pong + per-batch monotonic barrier.
// ---------------------------------------------------------------------------
__global__ __launch_bounds__(512, 1)
void scan_lds(const float* __restrict__ Wh, const float* __restrict__ bh,
              const float* __restrict__ ic, unsigned char* __restrict__ spk,
              float* __restrict__ h_state, unsigned int* __restrict__ bar,
              float* __restrict__ out)
{
    const int tid = threadIdx.x;
    const int b   = blockIdx.x & 15;
    const int blk = blockIdx.x >> 4;
    const int c0  = blk * 64;
    const int ci  = tid;                        // channel index (tid<64)

    __shared__ float wh_lds[512 * 64];          // [k][ci] 128 KB
    __shared__ float h_lds[512];

    for (int idx = tid; idx < 512 * 64; idx += 512)
        wh_lds[idx] = Wh[(size_t)(idx >> 6) * HDIM + c0 + (idx & 63)];

    float rbh = 0.f, v = 0.f, hn = 0.f, sp = 0.f;
    if (tid < 64) rbh = bh[c0 + ci];
    h_lds[tid] = 0.f;
    __syncthreads();

    for (int t = 0; t < S_LEN; ++t) {
        if (tid < 64) {
            const float icv = ic[((size_t)b * S_LEN + t) * HDIM + c0 + ci];

            float ah = 0.f;
#pragma unroll 8
            for (int k = 0; k < HDIM; ++k)
                ah = __fmaf_rn(h_lds[k], wh_lds[k * 64 + ci], ah);   // sgemm chain
            const float hc = __fadd_rn(ah, rbh);

            const float ho = h_lds[c0 + ci];
            const float t1 = __fadd_rn(-ho, icv);
            const float t2 = __fadd_rn(t1, hc);
            const float t3 = __fmul_rn(t2, 0.1f);
            hn = __fadd_rn(ho, t3);
            const float u1 = __fadd_rn(-v, hn);
            const float u2 = __fmul_rn(u1, 0.1f);
            const float vn = __fadd_rn(v, u2);
            sp = (vn >= 1.0f) ? 1.0f : 0.0f;
            v  = (vn >= 1.0f) ? 0.0f : vn;

            spk[((size_t)t * BATCH + b) * HDIM + c0 + ci] = (unsigned char)sp;
            __hip_atomic_store(&h_state[(size_t)((t + 1) & 1) * BATCH * HDIM + b * HDIM + c0 + ci],
                               hn, __ATOMIC_RELAXED, __HIP_MEMORY_SCOPE_AGENT);
        }
        __threadfence();
        __syncthreads();

        if (tid == 0) {
            __hip_atomic_fetch_add(&bar[b], 1u, __ATOMIC_ACQ_REL, __HIP_MEMORY_SCOPE_AGENT);
            const unsigned int target = (unsigned int)(NSLICE * (t + 1));
            long spin = 0;
            while (__hip_atomic_load(&bar[b], __ATOMIC_ACQUIRE, __HIP_MEMORY_SCOPE_AGENT) < target) {
                __builtin_amdgcn_s_sleep(1);
                if (++spin > 200000000L) break;   // fail loud, never hang
            }
        }
        __syncthreads();
        __threadfence();

        const float* hs = h_state + (size_t)((t + 1) & 1) * BATCH * HDIM + b * HDIM;
        h_lds[tid] = __hip_atomic_load(&hs[tid], __ATOMIC_RELAXED, __HIP_MEMORY_SCOPE_AGENT);
        __syncthreads();
    }

    if (tid < 64) {
        out[OUT_MAIN + (size_t)b * HDIM + c0 + ci]          = hn;   // h_f
        out[OUT_MAIN + 8192 + (size_t)b * HDIM + c0 + ci]   = v;    // v_f
        out[OUT_MAIN + 16384 + (size_t)b * HDIM + c0 + ci]  = sp;   // spikes_last
    }
}

// ---------------------------------------------------------------------------
// Fallback single-block scan (r14, proven pass) if ws is too small.
// ---------------------------------------------------------------------------
__global__ __launch_bounds__(512, 2)
void scan_f32(const float* __restrict__ x, const float* __restrict__ Wi,
              const float* __restrict__ bi, const float* __restrict__ Wh,
              const float* __restrict__ bh, unsigned char* __restrict__ spk,
              float* __restrict__ out)
{
    const int b = blockIdx.x;
    const int j = threadIdx.x;
    __shared__ float h_lds[HDIM];
    __shared__ float x_lds[HDIM];
    float v = 0.0f, hn = 0.0f, sp = 0.0f;
    const float rbh = bh[j], rbi = bi[j];
    h_lds[j] = 0.0f;
    const float* xb = x + (size_t)b * S_LEN * HDIM;
    for (int t = 0; t < S_LEN; ++t) {
        x_lds[j] = xb[(size_t)t * HDIM + j];
        __syncthreads();
        float ah = 0.0f, ax = 0.0f;
        const float* wj = Wh + j;
        const float* qj = Wi + j;
#pragma unroll 8
        for (int k = 0; k < HDIM; ++k) {
            ah = __fmaf_rn(h_lds[k], wj[(size_t)k * HDIM], ah);
            ax = __fadd_rn(ax, __fmul_rn(x_lds[k], qj[(size_t)k * HDIM]));
        }
        const float hc = __fadd_rn(ah, rbh);
        const float icv = __fadd_rn(ax, rbi);
        const float ho = h_lds[j];
        const float t1 = __fadd_rn(-ho, icv);
        const float t2 = __fadd_rn(t1, hc);
        const float t3 = __fmul_rn(t2, 0.1f);
        hn = __fadd_rn(ho, t3);
        const float u1 = __fadd_rn(-v, hn);
        const float u2 = __fmul_rn(u1, 0.1f);
        const float vn = __fadd_rn(v, u2);
        sp = (vn >= 1.0f) ? 1.0f : 0.0f;
        v  = (vn >= 1.0f) ? 0.0f : vn;
        spk[((size_t)t * BATCH + b) * HDIM + j] = (unsigned char)sp;
        __syncthreads();
        h_lds[j] = hn;
        __syncthreads();
    }
    out[OUT_MAIN + (size_t)b * HDIM + j]          = hn;
    out[OUT_MAIN + 8192 + (size_t)b * HDIM + j]   = v;
    out[OUT_MAIN + 16384 + (size_t)b * HDIM + j]  = sp;
}

// ---------------------------------------------------------------------------
// outputs[b,s,d] = sum_h spikes[s,b,h] * Wo[h*512+d] + bo[d]
// ---------------------------------------------------------------------------
__global__ __launch_bounds__(256, 2)
void out_gemm(const unsigned char* __restrict__ spikes, const float* __restrict__ Wo,
              const float* __restrict__ bo, float* __restrict__ out)
{
    const int s0 = blockIdx.x * 64;
    const int d0 = blockIdx.y * 64;
    const int b  = blockIdx.z;
    const int tid = threadIdx.x;

    __shared__ float sA[32][68];
    __shared__ float sB[32][68];

    float acc[4][4] = {};
    const int tm = tid >> 4, tn = tid & 15;
    const int m0 = tm * 4, n0 = tn * 4;

    for (int k0 = 0; k0 < HDIM; k0 += 32) {
        {
            const int m = tid >> 2, kq = (tid & 3) * 8;
            const unsigned char* pp = spikes + ((size_t)(s0 + m) * BATCH + b) * HDIM + k0 + kq;
            uchar4 u0 = *(const uchar4*)pp;
            uchar4 u1 = *(const uchar4*)(pp + 4);
            sA[kq+0][m] = (float)u0.x; sA[kq+1][m] = (float)u0.y;
            sA[kq+2][m] = (float)u0.z; sA[kq+3][m] = (float)u0.w;
            sA[kq+4][m] = (float)u1.x; sA[kq+5][m] = (float)u1.y;
            sA[kq+6][m] = (float)u1.z; sA[kq+7][m] = (float)u1.w;
        }
        {
            const int k = tid >> 3, n8 = (tid & 7) * 8;
            const float* pw = Wo + (size_t)(k0 + k) * HDIM + d0 + n8;
            float4 v0 = *(const float4*)pw;
            float4 v1 = *(const float4*)(pw + 4);
            *(float4*)&sB[k][n8]     = v0;
            *(float4*)&sB[k][n8 + 4] = v1;
        }
        __syncthreads();
#pragma unroll
        for (int k = 0; k < 32; ++k) {
            float a0 = sA[k][m0+0], a1 = sA[k][m0+1], a2 = sA[k][m0+2], a3 = sA[k][m0+3];
            float b0v = sB[k][n0+0], b1v = sB[k][n0+1], b2v = sB[k][n0+2], b3v = sB[k][n0+3];
            acc[0][0] += a0*b0v; acc[0][1] += a0*b1v; acc[0][2] += a0*b2v; acc[0][3] += a0*b3v;
            acc[1][0] += a1*b0v; acc[1][1] += a1*b1v; acc[1][2] += a1*b2v; acc[1][3] += a1*b3v;
            acc[2][0] += a2*b0v; acc[2][1] += a2*b1v; acc[2][2] += a2*b2v; acc[2][3] += a2*b3v;
            acc[3][0] += a3*b0v; acc[3][1] += a3*b1v; acc[3][2] += a3*b2v; acc[3][3] += a3*b3v;
        }
        __syncthreads();
    }

    float bov[4];
#pragma unroll
    for (int j = 0; j < 4; ++j) bov[j] = bo[d0 + n0 + j];
#pragma unroll
    for (int i = 0; i < 4; ++i) {
        size_t row = (size_t)b * S_LEN + s0 + m0 + i;
        float* o = out + row * HDIM + d0 + n0;
#pragma unroll
        for (int j = 0; j < 4; ++j)
            o[j] = acc[i][j] + bov[j];
    }
}

extern "C" void kernel_launch(void* const* d_in, const int* in_sizes, int n_in,
                              void* d_out, int out_size, void* d_ws, size_t ws_size,
                              hipStream_t stream)
{
    const float* x  = (const float*)d_in[0];
    const float* Wi = (const float*)d_in[1];
    const float* bi = (const float*)d_in[2];
    const float* Wh = (const float*)d_in[3];
    const float* bh = (const float*)d_in[4];
    const float* Wo = (const float*)d_in[5];
    const float* bo = (const float*)d_in[6];
    float* out = (float*)d_out;

    unsigned char* spikes  = (unsigned char*)d_ws + WS_SPK;
    float*         ic      = (float*)((char*)d_ws + WS_IC);
    float*         h_state = (float*)((char*)d_ws + WS_HST);
    unsigned int*  bar     = (unsigned int*)((char*)d_ws + WS_BAR);

    if (ws_size >= WS_NEED) {
        hipMemsetAsync((char*)d_ws + WS_BAR, 0, 256, stream);   // zero barrier counters
        ic_gemm<<<dim3((BATCH * S_LEN) / 16, HDIM / 64), dim3(256), 0, stream>>>(x, Wi, bi, ic);
        scan_lds<<<dim3(BATCH * NSLICE), dim3(512), 0, stream>>>(Wh, bh, ic, spikes, h_state, bar, out);
    } else {
        scan_f32<<<dim3(BATCH), dim3(512), 0, stream>>>(x, Wi, bi, Wh, bh, spikes, out);
    }

    out_gemm<<<dim3(S_LEN / 64, HDIM / 64, BATCH), dim3(256), 0, stream>>>(spikes, Wo, bo, out);
}

// Round 16
// 49420.312 us; speedup vs baseline: 2.7117x; 2.7117x over previous
//
#include <hip/hip_runtime.h>

#define S_LEN 4096
#define BATCH 16
#define HDIM  512
#define OUT_MAIN ((size_t)BATCH * S_LEN * HDIM)    // 33,554,432 f32 elements

#define WREG 192    // Wh rows 0..191 cached in VGPRs (per-channel column slice)
#define RLDS 30     // Wh rows 192..221 cached in LDS (60 KB)

// ws layout (ws >= 168 MB proven by r15 pathA execution):
//   [0, 33554432)            spikes u8 [S][B][H]
//   [33554432, +134217728)   ic f32 [B*S][H]
#define WS_SPK   ((size_t)0)
#define WS_IC    ((size_t)33554432)
#define WS_NEED  (WS_IC + (size_t)134217728)

// ---------------------------------------------------------------------------
// ic[b*S+t][j] = (sequential-d chain of fadd(fmul(x,w))) + bi[j]  — np-exact
// (bit-exact equivalence proven in r15: identical absmax to fused r14 path)
// ---------------------------------------------------------------------------
__global__ __launch_bounds__(256, 2)
void ic_gemm(const float* __restrict__ x, const float* __restrict__ Wi,
             const float* __restrict__ bi, float* __restrict__ ic)
{
    const int r0  = blockIdx.x * 16;          // rows over B*S
    const int j0  = blockIdx.y * 64;
    const int tid = threadIdx.x;
    const int jj  = tid & 63, ts = tid >> 6;

    __shared__ float xs[16][512];
#pragma unroll
    for (int kr = 0; kr < 32; ++kr) {
        int i = tid + 256 * kr;
        xs[i >> 9][i & 511] = x[(size_t)r0 * HDIM + i];
    }
    __syncthreads();

    float a0 = 0.f, a1 = 0.f, a2 = 0.f, a3 = 0.f;
    const float* wj = Wi + j0 + jj;
#pragma unroll 8
    for (int d = 0; d < HDIM; ++d) {
        const float w = wj[(size_t)d * HDIM];
        a0 = __fadd_rn(a0, __fmul_rn(xs[ts * 4 + 0][d], w));
        a1 = __fadd_rn(a1, __fmul_rn(xs[ts * 4 + 1][d], w));
        a2 = __fadd_rn(a2, __fmul_rn(xs[ts * 4 + 2][d], w));
        a3 = __fadd_rn(a3, __fmul_rn(xs[ts * 4 + 3][d], w));
    }
    const float bv = bi[j0 + jj];
    ic[(size_t)(r0 + ts * 4 + 0) * HDIM + j0 + jj] = __fadd_rn(a0, bv);
    ic[(size_t)(r0 + ts * 4 + 1) * HDIM + j0 + jj] = __fadd_rn(a1, bv);
    ic[(size_t)(r0 + ts * 4 + 2) * HDIM + j0 + jj] = __fadd_rn(a2, bv);
    ic[(size_t)(r0 + ts * 4 + 3) * HDIM + j0 + jj] = __fadd_rn(a3, bv);
}

// ---------------------------------------------------------------------------
// Scan: ONE block per batch (no cross-block sync), 512 threads = 1 channel each.
// Wh column cached: rows [0,WREG) in VGPRs, [WREG,WREG+RLDS) in LDS, rest from L2.
// Chain = np-exact sequential-k FMA (same value sequence as r14/r15 -> bit-identical).
// ---------------------------------------------------------------------------
__global__ __launch_bounds__(512, 2)
void scan_wreg(const float* __restrict__ Wh, const float* __restrict__ bh,
               const float* __restrict__ ic, unsigned char* __restrict__ spk,
               float* __restrict__ out)
{
    const int b = blockIdx.x;
    const int j = threadIdx.x;

    __shared__ float h_lds[HDIM];
    __shared__ float wh_lds[RLDS][HDIM];     // 60 KB

    const float* wj = Wh + j;                // column j, stride HDIM

    float wreg[WREG];
#pragma unroll
    for (int k = 0; k < WREG; ++k)
        wreg[k] = wj[(size_t)k * HDIM];
    for (int r = 0; r < RLDS; ++r)
        wh_lds[r][j] = Wh[(size_t)(WREG + r) * HDIM + j];

    float v = 0.0f, hn = 0.0f, sp = 0.0f;
    const float rbh = bh[j];
    h_lds[j] = 0.0f;

    const float* icb = ic + (size_t)b * S_LEN * HDIM + j;
    float icv = icb[0];
    __syncthreads();

    for (int t = 0; t < S_LEN; ++t) {
        // prefetch next step's ic element (independent of chain)
        float icn = 0.0f;
        if (t + 1 < S_LEN) icn = icb[(size_t)(t + 1) * HDIM];

        // np-exact sequential-k FMA chain, k = 0..511 in order
        float ah = 0.0f;
#pragma unroll
        for (int k = 0; k < WREG; ++k)
            ah = __fmaf_rn(h_lds[k], wreg[k], ah);
#pragma unroll
        for (int r = 0; r < RLDS; ++r)
            ah = __fmaf_rn(h_lds[WREG + r], wh_lds[r][j], ah);
#pragma unroll 8
        for (int k = WREG + RLDS; k < HDIM; ++k)
            ah = __fmaf_rn(h_lds[k], wj[(size_t)k * HDIM], ah);

        const float hc = __fadd_rn(ah, rbh);     // (h@Wh) + bh
        const float ho = h_lds[j];
        const float t1 = __fadd_rn(-ho, icv);    // -h + ic
        const float t2 = __fadd_rn(t1, hc);      // ... + hc
        const float t3 = __fmul_rn(t2, 0.1f);    // * inv_tau
        hn = __fadd_rn(ho, t3);                  // h_new
        const float u1 = __fadd_rn(-v, hn);
        const float u2 = __fmul_rn(u1, 0.1f);
        const float vn = __fadd_rn(v, u2);
        sp = (vn >= 1.0f) ? 1.0f : 0.0f;
        v  = (vn >= 1.0f) ? 0.0f : vn;

        spk[((size_t)t * BATCH + b) * HDIM + j] = (unsigned char)sp;

        __syncthreads();          // all chain reads of h_lds done
        h_lds[j] = hn;
        icv = icn;
        __syncthreads();          // h_{t+1} visible
    }

    out[OUT_MAIN + (size_t)b * HDIM + j]          = hn;   // h_f
    out[OUT_MAIN + 8192 + (size_t)b * HDIM + j]   = v;    // v_f
    out[OUT_MAIN + 16384 + (size_t)b * HDIM + j]  = sp;   // spikes_last
}

// ---------------------------------------------------------------------------
// Fallback single-block fused scan (r14, proven) if ws is too small.
// ---------------------------------------------------------------------------
__global__ __launch_bounds__(512, 2)
void scan_f32(const float* __restrict__ x, const float* __restrict__ Wi,
              const float* __restrict__ bi, const float* __restrict__ Wh,
              const float* __restrict__ bh, unsigned char* __restrict__ spk,
              float* __restrict__ out)
{
    const int b = blockIdx.x;
    const int j = threadIdx.x;
    __shared__ float h_lds[HDIM];
    __shared__ float x_lds[HDIM];
    float v = 0.0f, hn = 0.0f, sp = 0.0f;
    const float rbh = bh[j], rbi = bi[j];
    h_lds[j] = 0.0f;
    const float* xb = x + (size_t)b * S_LEN * HDIM;
    for (int t = 0; t < S_LEN; ++t) {
        x_lds[j] = xb[(size_t)t * HDIM + j];
        __syncthreads();
        float ah = 0.0f, ax = 0.0f;
        const float* wj = Wh + j;
        const float* qj = Wi + j;
#pragma unroll 8
        for (int k = 0; k < HDIM; ++k) {
            ah = __fmaf_rn(h_lds[k], wj[(size_t)k * HDIM], ah);
            ax = __fadd_rn(ax, __fmul_rn(x_lds[k], qj[(size_t)k * HDIM]));
        }
        const float hc = __fadd_rn(ah, rbh);
        const float icv = __fadd_rn(ax, rbi);
        const float ho = h_lds[j];
        const float t1 = __fadd_rn(-ho, icv);
        const float t2 = __fadd_rn(t1, hc);
        const float t3 = __fmul_rn(t2, 0.1f);
        hn = __fadd_rn(ho, t3);
        const float u1 = __fadd_rn(-v, hn);
        const float u2 = __fmul_rn(u1, 0.1f);
        const float vn = __fadd_rn(v, u2);
        sp = (vn >= 1.0f) ? 1.0f : 0.0f;
        v  = (vn >= 1.0f) ? 0.0f : vn;
        spk[((size_t)t * BATCH + b) * HDIM + j] = (unsigned char)sp;
        __syncthreads();
        h_lds[j] = hn;
        __syncthreads();
    }
    out[OUT_MAIN + (size_t)b * HDIM + j]          = hn;
    out[OUT_MAIN + 8192 + (size_t)b * HDIM + j]   = v;
    out[OUT_MAIN + 16384 + (size_t)b * HDIM + j]  = sp;
}

// ---------------------------------------------------------------------------
// outputs[b,s,d] = sum_h spikes[s,b,h] * Wo[h*512+d] + bo[d]
// ---------------------------------------------------------------------------
__global__ __launch_bounds__(256, 2)
void out_gemm(const unsigned char* __restrict__ spikes, const float* __restrict__ Wo,
              const float* __restrict__ bo, float* __restrict__ out)
{
    const int s0 = blockIdx.x * 64;
    const int d0 = blockIdx.y * 64;
    const int b  = blockIdx.z;
    const int tid = threadIdx.x;

    __shared__ float sA[32][68];
    __shared__ float sB[32][68];

    float acc[4][4] = {};
    const int tm = tid >> 4, tn = tid & 15;
    const int m0 = tm * 4, n0 = tn * 4;

    for (int k0 = 0; k0 < HDIM; k0 += 32) {
        {
            const int m = tid >> 2, kq = (tid & 3) * 8;
            const unsigned char* pp = spikes + ((size_t)(s0 + m) * BATCH + b) * HDIM + k0 + kq;
            uchar4 u0 = *(const uchar4*)pp;
            uchar4 u1 = *(const uchar4*)(pp + 4);
            sA[kq+0][m] = (float)u0.x; sA[kq+1][m] = (float)u0.y;
            sA[kq+2][m] = (float)u0.z; sA[kq+3][m] = (float)u0.w;
            sA[kq+4][m] = (float)u1.x; sA[kq+5][m] = (float)u1.y;
            sA[kq+6][m] = (float)u1.z; sA[kq+7][m] = (float)u1.w;
        }
        {
            const int k = tid >> 3, n8 = (tid & 7) * 8;
            const float* pw = Wo + (size_t)(k0 + k) * HDIM + d0 + n8;
            float4 v0 = *(const float4*)pw;
            float4 v1 = *(const float4*)(pw + 4);
            *(float4*)&sB[k][n8]     = v0;
            *(float4*)&sB[k][n8 + 4] = v1;
        }
        __syncthreads();
#pragma unroll
        for (int k = 0; k < 32; ++k) {
            float a0 = sA[k][m0+0], a1 = sA[k][m0+1], a2 = sA[k][m0+2], a3 = sA[k][m0+3];
            float b0v = sB[k][n0+0], b1v = sB[k][n0+1], b2v = sB[k][n0+2], b3v = sB[k][n0+3];
            acc[0][0] += a0*b0v; acc[0][1] += a0*b1v; acc[0][2] += a0*b2v; acc[0][3] += a0*b3v;
            acc[1][0] += a1*b0v; acc[1][1] += a1*b1v; acc[1][2] += a1*b2v; acc[1][3] += a1*b3v;
            acc[2][0] += a2*b0v; acc[2][1] += a2*b1v; acc[2][2] += a2*b2v; acc[2][3] += a2*b3v;
            acc[3][0] += a3*b0v; acc[3][1] += a3*b1v; acc[3][2] += a3*b2v; acc[3][3] += a3*b3v;
        }
        __syncthreads();
    }

    float bov[4];
#pragma unroll
    for (int j = 0; j < 4; ++j) bov[j] = bo[d0 + n0 + j];
#pragma unroll
    for (int i = 0; i < 4; ++i) {
        size_t row = (size_t)b * S_LEN + s0 + m0 + i;
        float* o = out + row * HDIM + d0 + n0;
#pragma unroll
        for (int j = 0; j < 4; ++j)
            o[j] = acc[i][j] + bov[j];
    }
}

extern "C" void kernel_launch(void* const* d_in, const int* in_sizes, int n_in,
                              void* d_out, int out_size, void* d_ws, size_t ws_size,
                              hipStream_t stream)
{
    const float* x  = (const float*)d_in[0];
    const float* Wi = (const float*)d_in[1];
    const float* bi = (const float*)d_in[2];
    const float* Wh = (const float*)d_in[3];
    const float* bh = (const float*)d_in[4];
    const float* Wo = (const float*)d_in[5];
    const float* bo = (const float*)d_in[6];
    float* out = (float*)d_out;

    unsigned char* spikes = (unsigned char*)d_ws + WS_SPK;
    float*         ic     = (float*)((char*)d_ws + WS_IC);

    if (ws_size >= WS_NEED) {
        ic_gemm<<<dim3((BATCH * S_LEN) / 16, HDIM / 64), dim3(256), 0, stream>>>(x, Wi, bi, ic);
        scan_wreg<<<dim3(BATCH), dim3(512), 0, stream>>>(Wh, bh, ic, spikes, out);
    } else {
        scan_f32<<<dim3(BATCH), dim3(512), 0, stream>>>(x, Wi, bi, Wh, bh, spikes, out);
    }

    out_gemm<<<dim3(S_LEN / 64, HDIM / 64, BATCH), dim3(256), 0, stream>>>(spikes, Wo, bo, out);
}

// Round 17
// 30132.260 us; speedup vs baseline: 4.4475x; 1.6401x over previous
//
#include <hip/hip_runtime.h>

#define S_LEN 4096
#define BATCH 16
#define HDIM  512
#define NSLICE 8                                   // blocks per batch
#define OUT_MAIN ((size_t)BATCH * S_LEN * HDIM)    // 33,554,432 f32 elements

// ws layout (ws >= 304MB proven by r10 pathA):
#define WS_SPK   ((size_t)0)                            // spikes u8 [S][B][H]
#define WS_IC    ((size_t)33554432)                     // ic f32 [B*S][H] (128MB)
#define WS_HST   (WS_IC + (size_t)134217728)            // h f32 [2][B][H] (64KB)
#define WS_BAR   (WS_HST + (size_t)65536)               // bar u32[16] padded 128B (2KB)
#define WS_NEED  (WS_BAR + (size_t)2048)

// ---------------------------------------------------------------------------
// ic[b*S+t][j] = (sequential-d chain of fadd(fmul(x,w))) + bi[j]  — np-exact
// ---------------------------------------------------------------------------
__global__ __launch_bounds__(256, 2)
void ic_gemm(const float* __restrict__ x, const float* __restrict__ Wi,
             const float* __restrict__ bi, float* __restrict__ ic)
{
    const int r0  = blockIdx.x * 16;          // rows over B*S
    const int j0  = blockIdx.y * 64;
    const int tid = threadIdx.x;
    const int jj  = tid & 63, ts = tid >> 6;

    __shared__ float xs[16][512];
#pragma unroll
    for (int kr = 0; kr < 32; ++kr) {
        int i = tid + 256 * kr;
        xs[i >> 9][i & 511] = x[(size_t)r0 * HDIM + i];
    }
    __syncthreads();

    float a0 = 0.f, a1 = 0.f, a2 = 0.f, a3 = 0.f;
    const float* wj = Wi + j0 + jj;
#pragma unroll 8
    for (int d = 0; d < HDIM; ++d) {
        const float w = wj[(size_t)d * HDIM];
        a0 = __fadd_rn(a0, __fmul_rn(xs[ts * 4 + 0][d], w));
        a1 = __fadd_rn(a1, __fmul_rn(xs[ts * 4 + 1][d], w));
        a2 = __fadd_rn(a2, __fmul_rn(xs[ts * 4 + 2][d], w));
        a3 = __fadd_rn(a3, __fmul_rn(xs[ts * 4 + 3][d], w));
    }
    const float bv = bi[j0 + jj];
    ic[(size_t)(r0 + ts * 4 + 0) * HDIM + j0 + jj] = __fadd_rn(a0, bv);
    ic[(size_t)(r0 + ts * 4 + 1) * HDIM + j0 + jj] = __fadd_rn(a1, bv);
    ic[(size_t)(r0 + ts * 4 + 2) * HDIM + j0 + jj] = __fadd_rn(a2, bv);
    ic[(size_t)(r0 + ts * 4 + 3) * HDIM + j0 + jj] = __fadd_rn(a3, bv);
}

// ---------------------------------------------------------------------------
// Scan: 8 blocks/batch, 64 channels each, FULL Wh slice resident in LDS.
// Exchange protocol: relaxed agent stores (bypass L1) -> __syncthreads (vmcnt
// drain) -> lane0 release fetch_add -> relaxed spin -> lane0 acquire ->
// relaxed agent reloads. No thread-wide fences; padded per-batch counters.
// Slices of batch b sit at blockIdx ≡ b (mod 16) -> same XCD under %8 RR.
// ---------------------------------------------------------------------------
__global__ __launch_bounds__(256, 1)
void scan_x8(const float* __restrict__ Wh, const float* __restrict__ bh,
             const float* __restrict__ ic, unsigned char* __restrict__ spk,
             float* __restrict__ h_state, unsigned int* __restrict__ bar,
             float* __restrict__ out)
{
    const int tid = threadIdx.x;
    const int b   = blockIdx.x & 15;      // batch
    const int sl  = blockIdx.x >> 4;      // slice 0..7
    const int c0  = sl * 64;

    __shared__ float wh_lds[64 * 516];    // [ci][k], row stride 516 (2064B, 16B-aligned)
    __shared__ float h_lds[512];

    // stage Wh slice once: wh_lds[ci][k] = Wh[k*512 + c0 + ci] (coalesced reads)
    for (int i = tid; i < 64 * 512; i += 256) {
        const int k = i >> 6, ci = i & 63;
        wh_lds[ci * 516 + k] = Wh[(size_t)k * HDIM + c0 + ci];
    }
    float rbh = 0.f, v = 0.f, hn = 0.f, sp = 0.f;
    if (tid < 64) rbh = bh[c0 + tid];
    h_lds[tid] = 0.f; h_lds[tid + 256] = 0.f;
    __syncthreads();

    unsigned int* barp = bar + b * 32;    // 128B-padded counter per batch
    const float* icb = ic + (size_t)b * S_LEN * HDIM + c0;

    for (int t = 0; t < S_LEN; ++t) {
        if (tid < 64) {
            const float icv = icb[(size_t)t * HDIM + tid];   // early, hides latency

            // np-exact sequential-k FMA chain (k = 0..511 in order)
            const float* wrow = &wh_lds[tid * 516];
            float ah = 0.f;
#pragma unroll 32
            for (int k4 = 0; k4 < 128; ++k4) {
                const float4 wv = *(const float4*)(wrow + 4 * k4);
                const float4 hv = *(const float4*)(&h_lds[4 * k4]);
                ah = __fmaf_rn(hv.x, wv.x, ah);
                ah = __fmaf_rn(hv.y, wv.y, ah);
                ah = __fmaf_rn(hv.z, wv.z, ah);
                ah = __fmaf_rn(hv.w, wv.w, ah);
            }
            const float hc = __fadd_rn(ah, rbh);     // (h@Wh) + bh
            const float ho = h_lds[c0 + tid];
            const float t1 = __fadd_rn(-ho, icv);    // -h + ic
            const float t2 = __fadd_rn(t1, hc);      // ... + hc
            const float t3 = __fmul_rn(t2, 0.1f);    // * inv_tau
            hn = __fadd_rn(ho, t3);                  // h_new
            const float u1 = __fadd_rn(-v, hn);
            const float u2 = __fmul_rn(u1, 0.1f);
            const float vn = __fadd_rn(v, u2);
            sp = (vn >= 1.0f) ? 1.0f : 0.0f;
            v  = (vn >= 1.0f) ? 0.0f : vn;

            spk[((size_t)t * BATCH + b) * HDIM + c0 + tid] = (unsigned char)sp;
            __hip_atomic_store(&h_state[(size_t)((t + 1) & 1) * (BATCH * HDIM) + b * HDIM + c0 + tid],
                               hn, __ATOMIC_RELAXED, __HIP_MEMORY_SCOPE_AGENT);
        }
        __syncthreads();   // drains every wave's vmcnt -> h stores committed

        if (tid == 0) {
            __hip_atomic_fetch_add(barp, 1u, __ATOMIC_RELEASE, __HIP_MEMORY_SCOPE_AGENT);
            const unsigned int target = (unsigned int)(NSLICE * (t + 1));
            long spin = 0;
            while (__hip_atomic_load(barp, __ATOMIC_RELAXED, __HIP_MEMORY_SCOPE_AGENT) < target) {
                __builtin_amdgcn_s_sleep(1);
                if (++spin > 100000000L) break;   // fail loud, never hang
            }
            (void)__hip_atomic_load(barp, __ATOMIC_ACQUIRE, __HIP_MEMORY_SCOPE_AGENT);
        }
        __syncthreads();

        // restage full h (bypass-L1 loads read the shared L2)
        const float* hs = h_state + (size_t)((t + 1) & 1) * (BATCH * HDIM) + b * HDIM;
        h_lds[tid]       = __hip_atomic_load(hs + tid,       __ATOMIC_RELAXED, __HIP_MEMORY_SCOPE_AGENT);
        h_lds[tid + 256] = __hip_atomic_load(hs + tid + 256, __ATOMIC_RELAXED, __HIP_MEMORY_SCOPE_AGENT);
        __syncthreads();
    }

    if (tid < 64) {
        out[OUT_MAIN + (size_t)b * HDIM + c0 + tid]          = hn;   // h_f
        out[OUT_MAIN + 8192 + (size_t)b * HDIM + c0 + tid]   = v;    // v_f
        out[OUT_MAIN + 16384 + (size_t)b * HDIM + c0 + tid]  = sp;   // spikes_last
    }
}

// ---------------------------------------------------------------------------
// Fallback single-block fused scan (r14, proven) if ws is too small.
// ---------------------------------------------------------------------------
__global__ __launch_bounds__(512, 2)
void scan_f32(const float* __restrict__ x, const float* __restrict__ Wi,
              const float* __restrict__ bi, const float* __restrict__ Wh,
              const float* __restrict__ bh, unsigned char* __restrict__ spk,
              float* __restrict__ out)
{
    const int b = blockIdx.x;
    const int j = threadIdx.x;
    __shared__ float h_lds[HDIM];
    __shared__ float x_lds[HDIM];
    float v = 0.0f, hn = 0.0f, sp = 0.0f;
    const float rbh = bh[j], rbi = bi[j];
    h_lds[j] = 0.0f;
    const float* xb = x + (size_t)b * S_LEN * HDIM;
    for (int t = 0; t < S_LEN; ++t) {
        x_lds[j] = xb[(size_t)t * HDIM + j];
        __syncthreads();
        float ah = 0.0f, ax = 0.0f;
        const float* wj = Wh + j;
        const float* qj = Wi + j;
#pragma unroll 8
        for (int k = 0; k < HDIM; ++k) {
            ah = __fmaf_rn(h_lds[k], wj[(size_t)k * HDIM], ah);
            ax = __fadd_rn(ax, __fmul_rn(x_lds[k], qj[(size_t)k * HDIM]));
        }
        const float hc = __fadd_rn(ah, rbh);
        const float icv = __fadd_rn(ax, rbi);
        const float ho = h_lds[j];
        const float t1 = __fadd_rn(-ho, icv);
        const float t2 = __fadd_rn(t1, hc);
        const float t3 = __fmul_rn(t2, 0.1f);
        hn = __fadd_rn(ho, t3);
        const float u1 = __fadd_rn(-v, hn);
        const float u2 = __fmul_rn(u1, 0.1f);
        const float vn = __fadd_rn(v, u2);
        sp = (vn >= 1.0f) ? 1.0f : 0.0f;
        v  = (vn >= 1.0f) ? 0.0f : vn;
        spk[((size_t)t * BATCH + b) * HDIM + j] = (unsigned char)sp;
        __syncthreads();
        h_lds[j] = hn;
        __syncthreads();
    }
    out[OUT_MAIN + (size_t)b * HDIM + j]          = hn;
    out[OUT_MAIN + 8192 + (size_t)b * HDIM + j]   = v;
    out[OUT_MAIN + 16384 + (size_t)b * HDIM + j]  = sp;
}

// ---------------------------------------------------------------------------
// outputs[b,s,d] = sum_h spikes[s,b,h] * Wo[h*512+d] + bo[d]
// ---------------------------------------------------------------------------
__global__ __launch_bounds__(256, 2)
void out_gemm(const unsigned char* __restrict__ spikes, const float* __restrict__ Wo,
              const float* __restrict__ bo, float* __restrict__ out)
{
    const int s0 = blockIdx.x * 64;
    const int d0 = blockIdx.y * 64;
    const int b  = blockIdx.z;
    const int tid = threadIdx.x;

    __shared__ float sA[32][68];
    __shared__ float sB[32][68];

    float acc[4][4] = {};
    const int tm = tid >> 4, tn = tid & 15;
    const int m0 = tm * 4, n0 = tn * 4;

    for (int k0 = 0; k0 < HDIM; k0 += 32) {
        {
            const int m = tid >> 2, kq = (tid & 3) * 8;
            const unsigned char* pp = spikes + ((size_t)(s0 + m) * BATCH + b) * HDIM + k0 + kq;
            uchar4 u0 = *(const uchar4*)pp;
            uchar4 u1 = *(const uchar4*)(pp + 4);
            sA[kq+0][m] = (float)u0.x; sA[kq+1][m] = (float)u0.y;
            sA[kq+2][m] = (float)u0.z; sA[kq+3][m] = (float)u0.w;
            sA[kq+4][m] = (float)u1.x; sA[kq+5][m] = (float)u1.y;
            sA[kq+6][m] = (float)u1.z; sA[kq+7][m] = (float)u1.w;
        }
        {
            const int k = tid >> 3, n8 = (tid & 7) * 8;
            const float* pw = Wo + (size_t)(k0 + k) * HDIM + d0 + n8;
            float4 v0 = *(const float4*)pw;
            float4 v1 = *(const float4*)(pw + 4);
            *(float4*)&sB[k][n8]     = v0;
            *(float4*)&sB[k][n8 + 4] = v1;
        }
        __syncthreads();
#pragma unroll
        for (int k = 0; k < 32; ++k) {
            float a0 = sA[k][m0+0], a1 = sA[k][m0+1], a2 = sA[k][m0+2], a3 = sA[k][m0+3];
            float b0v = sB[k][n0+0], b1v = sB[k][n0+1], b2v = sB[k][n0+2], b3v = sB[k][n0+3];
            acc[0][0] += a0*b0v; acc[0][1] += a0*b1v; acc[0][2] += a0*b2v; acc[0][3] += a0*b3v;
            acc[1][0] += a1*b0v; acc[1][1] += a1*b1v; acc[1][2] += a1*b2v; acc[1][3] += a1*b3v;
            acc[2][0] += a2*b0v; acc[2][1] += a2*b1v; acc[2][2] += a2*b2v; acc[2][3] += a2*b3v;
            acc[3][0] += a3*b0v; acc[3][1] += a3*b1v; acc[3][2] += a3*b2v; acc[3][3] += a3*b3v;
        }
        __syncthreads();
    }

    float bov[4];
#pragma unroll
    for (int j = 0; j < 4; ++j) bov[j] = bo[d0 + n0 + j];
#pragma unroll
    for (int i = 0; i < 4; ++i) {
        size_t row = (size_t)b * S_LEN + s0 + m0 + i;
        float* o = out + row * HDIM + d0 + n0;
#pragma unroll
        for (int j = 0; j < 4; ++j)
            o[j] = acc[i][j] + bov[j];
    }
}

extern "C" void kernel_launch(void* const* d_in, const int* in_sizes, int n_in,
                              void* d_out, int out_size, void* d_ws, size_t ws_size,
                              hipStream_t stream)
{
    const float* x  = (const float*)d_in[0];
    const float* Wi = (const float*)d_in[1];
    const float* bi = (const float*)d_in[2];
    const float* Wh = (const float*)d_in[3];
    const float* bh = (const float*)d_in[4];
    const float* Wo = (const float*)d_in[5];
    const float* bo = (const float*)d_in[6];
    float* out = (float*)d_out;

    unsigned char* spikes  = (unsigned char*)d_ws + WS_SPK;
    float*         ic      = (float*)((char*)d_ws + WS_IC);
    float*         h_state = (float*)((char*)d_ws + WS_HST);
    unsigned int*  bar     = (unsigned int*)((char*)d_ws + WS_BAR);

    if (ws_size >= WS_NEED) {
        hipMemsetAsync((char*)d_ws + WS_BAR, 0, 2048, stream);
        ic_gemm<<<dim3((BATCH * S_LEN) / 16, HDIM / 64), dim3(256), 0, stream>>>(x, Wi, bi, ic);
        scan_x8<<<dim3(BATCH * NSLICE), dim3(256), 0, stream>>>(Wh, bh, ic, spikes, h_state, bar, out);
    } else {
        scan_f32<<<dim3(BATCH), dim3(512), 0, stream>>>(x, Wi, bi, Wh, bh, spikes, out);
    }

    out_gemm<<<dim3(S_LEN / 64, HDIM / 64, BATCH), dim3(256), 0, stream>>>(spikes, Wo, bo, out);
}